// Round 3
// baseline (579.149 us; speedup 1.0000x reference)
//
#include <hip/hip_runtime.h>
#include <hip/hip_bf16.h>
#include <math.h>

#define NN 50000
#define NE 1600000
#define FIN 128
#define EH 20
#define DH 64

// ---------------- kernels ----------------

// detect edge_index element width (int64 vs int32)
__global__ void k_flag(int* flag, const void* ei) {
    const int* w = (const int*)ei;
    int all0 = 1;
    for (int j = 1; j < 128; j += 2) all0 &= (w[j] == 0);
    *flag = all0;  // 1 => int64 layout (high words zero), 0 => int32
}

// convert edge_index to int32 r/c arrays and count in-degree of col
__global__ void k_cvt(const void* ei, const int* flag, int* r32, int* c32, int* cnt) {
    int e = blockIdx.x * blockDim.x + threadIdx.x;
    if (e >= NE) return;
    int r, c;
    if (*flag) {
        const long long* p = (const long long*)ei;
        r = (int)p[e];
        c = (int)p[NE + e];
    } else {
        const int* p = (const int*)ei;
        r = p[e];
        c = p[NE + e];
    }
    r32[e] = r;
    c32[e] = c;
    atomicAdd(&cnt[c], 1);
}

// single-block exclusive scan of cnt[NN] -> off[NN+1]
__global__ void k_scan(const int* __restrict__ cnt, int* __restrict__ off) {
    __shared__ int part[1024];
    const int t = threadIdx.x;
    const int CH = (NN + 1023) / 1024;  // 49
    const int base = t * CH;
    int s = 0;
    for (int i = 0; i < CH; ++i) {
        int idx = base + i;
        if (idx < NN) s += cnt[idx];
    }
    part[t] = s;
    __syncthreads();
    for (int d = 1; d < 1024; d <<= 1) {
        int v = 0;
        if (t >= d) v = part[t - d];
        __syncthreads();
        if (t >= d) part[t] += v;
        __syncthreads();
    }
    int excl = (t == 0) ? 0 : part[t - 1];
    for (int i = 0; i < CH; ++i) {
        int idx = base + i;
        if (idx < NN) {
            off[idx] = excl;
            excl += cnt[idx];
        }
    }
    if (t == 1023) off[NN] = excl;  // == NE
}

// hs[n,k] = dinv[n] * dot(x[n,:], W[:,k]) ; 32 threads per node, k = lane (k<20 active)
__global__ void k_xw(const float* __restrict__ x, const float* __restrict__ W,
                     const int* __restrict__ cnt, float* __restrict__ hs) {
    int t = blockIdx.x * blockDim.x + threadIdx.x;
    int n = t >> 5;
    int k = t & 31;
    if (n >= NN || k >= EH) return;
    const float4* xr = (const float4*)(x + (size_t)n * FIN);
    float acc = 0.f;
#pragma unroll
    for (int j4 = 0; j4 < FIN / 4; ++j4) {
        float4 v = xr[j4];
        acc = fmaf(v.x, W[(4 * j4 + 0) * EH + k], acc);
        acc = fmaf(v.y, W[(4 * j4 + 1) * EH + k], acc);
        acc = fmaf(v.z, W[(4 * j4 + 2) * EH + k], acc);
        acc = fmaf(v.w, W[(4 * j4 + 3) * EH + k], acc);
    }
    float dinv = rsqrtf(1.0f + (float)cnt[n]);
    hs[n * EH + k] = dinv * acc;
}

// bucket-fill CSR: re[off[c] + cursor[c]++] = {r, e}
__global__ void k_fill(const int* __restrict__ r32, const int* __restrict__ c32,
                       const int* __restrict__ off, int* __restrict__ cursor,
                       int2* __restrict__ re) {
    int e = blockIdx.x * blockDim.x + threadIdx.x;
    if (e >= NE) return;
    int c = c32[e];
    int pos = off[c] + atomicAdd(&cursor[c], 1);
    re[pos] = make_int2(r32[e], e);
}

// per-node gather + bias + relu: h1[n,k] = relu(dinv[n]*(hs[n,k] + sum_r hs[r,k]) + b[k])
__global__ void k_gather(const int* __restrict__ off, const int2* __restrict__ re,
                         const int* __restrict__ cnt, const float* __restrict__ hs,
                         const float* __restrict__ bg, float* __restrict__ h1) {
    int t = blockIdx.x * blockDim.x + threadIdx.x;
    int n = t >> 5;
    int k = t & 31;
    if (n >= NN || k >= EH) return;
    float acc = hs[n * EH + k];  // self-loop term (already carries dinv[n])
    int e0 = off[n], e1 = off[n + 1];
    for (int e = e0; e < e1; ++e) {
        int r = re[e].x;
        acc += hs[r * EH + k];
    }
    float dinv = rsqrtf(1.0f + (float)cnt[n]);
    h1[n * EH + k] = fmaxf(fmaf(dinv, acc, bg[k]), 0.f);
}

// cn[j] = h1[node_id,:] @ W1[40:60, j] + b1[j]
__global__ void k_cn(const float* __restrict__ h1, const float* __restrict__ W1,
                     const float* __restrict__ b1, const void* nid_p,
                     float* __restrict__ cn) {
    int j = threadIdx.x;  // 64 threads
    int nid = *(const int*)nid_p;  // low 32 bits valid for int32 or int64 LE
    const float* hr = h1 + (size_t)nid * EH;
    float acc = b1[j];
#pragma unroll
    for (int k = 0; k < EH; ++k) acc = fmaf(hr[k], W1[(2 * EH + k) * DH + j], acc);
    cn[j] = acc;
}

// A16[n,j] = bf16(h1[n,:] @ W1[0:20, j]);  B16[n,j] = bf16(cn[j] + h1[n,:] @ W1[20:40, j])
__global__ void k_ab(const float* __restrict__ h1, const float* __restrict__ W1,
                     const float* __restrict__ cn,
                     __hip_bfloat16* __restrict__ A16, __hip_bfloat16* __restrict__ B16) {
    int t = blockIdx.x * blockDim.x + threadIdx.x;
    int n = t >> 6;
    int j = t & 63;
    if (n >= NN) return;
    const float* hr = h1 + (size_t)n * EH;
    float a = 0.f, b = cn[j];
#pragma unroll
    for (int k = 0; k < EH; ++k) {
        float hv = hr[k];
        a = fmaf(hv, W1[k * DH + j], a);
        b = fmaf(hv, W1[(EH + k) * DH + j], b);
    }
    A16[(size_t)n * DH + j] = __float2bfloat16(a);
    B16[(size_t)n * DH + j] = __float2bfloat16(b);
}

__device__ __forceinline__ float4 bf4_to_f4(ushort4 u) {
    float4 f;
    f.x = __uint_as_float((unsigned)u.x << 16);
    f.y = __uint_as_float((unsigned)u.y << 16);
    f.z = __uint_as_float((unsigned)u.z << 16);
    f.w = __uint_as_float((unsigned)u.w << 16);
    return f;
}

// per-dst-node edge decoder: 16 lanes per node c; B'[c] in regs, loop edges reading A[r].
__global__ void k_edge(const int* __restrict__ off, const int2* __restrict__ re,
                       const __hip_bfloat16* __restrict__ A16,
                       const __hip_bfloat16* __restrict__ B16,
                       const float* __restrict__ W2, const float* __restrict__ b2,
                       const float* __restrict__ eps, float* __restrict__ out) {
    int t = blockIdx.x * blockDim.x + threadIdx.x;
    int c = t >> 4;
    if (c >= NN) return;
    int lane = t & 15;
    float4 bc = bf4_to_f4(*(const ushort4*)(B16 + (size_t)c * DH + lane * 4));
    float4 w = *(const float4*)(W2 + lane * 4);
    float bias2 = b2[0];
    int e0 = off[c], e1 = off[c + 1];
    for (int pos = e0; pos < e1; ++pos) {
        int2 pe = re[pos];
        float4 a = bf4_to_f4(*(const ushort4*)(A16 + (size_t)pe.x * DH + lane * 4));
        float p = fmaxf(a.x + bc.x, 0.f) * w.x
                + fmaxf(a.y + bc.y, 0.f) * w.y
                + fmaxf(a.z + bc.z, 0.f) * w.z
                + fmaxf(a.w + bc.w, 0.f) * w.w;
        p += __shfl_xor(p, 1);
        p += __shfl_xor(p, 2);
        p += __shfl_xor(p, 4);
        p += __shfl_xor(p, 8);
        if (lane == 0) {
            float ep = eps[pe.y];
            // e = (bias-(1-bias))*eps + (1-bias), bias=1e-4
            float ee = fmaf(-0.9998f, ep, 0.9999f);
            float gate = logf(ee) - log1pf(-ee) + p + bias2;
            out[pe.y] = 1.0f / (1.0f + expf(-gate));
        }
    }
}

// ---------------- launch ----------------

extern "C" void kernel_launch(void* const* d_in, const int* in_sizes, int n_in,
                              void* d_out, int out_size, void* d_ws, size_t ws_size,
                              hipStream_t stream) {
    const float* x   = (const float*)d_in[0];
    const void*  ei  = d_in[1];
    const void*  nid = d_in[2];
    const float* eps = (const float*)d_in[3];
    const float* Wg  = (const float*)d_in[4];
    const float* bg  = (const float*)d_in[5];
    const float* W1  = (const float*)d_in[6];
    const float* b1  = (const float*)d_in[7];
    const float* W2  = (const float*)d_in[8];
    const float* b2  = (const float*)d_in[9];
    float* out = (float*)d_out;

    float* ws = (float*)d_ws;
    // re [0, 3.2M) ; r32/A16 [3.2M, 4.8M) ; c32/B16 [4.8M, 6.4M) — A16/B16
    // overwrite r32/c32 only after k_fill (their last use). hs/h1 follow.
    int2* re = (int2*)(ws + 0);
    int*  r32 = (int*)(ws + 3200000);
    int*  c32 = (int*)(ws + 4800000);
    __hip_bfloat16* A16 = (__hip_bfloat16*)(ws + 3200000);
    __hip_bfloat16* B16 = (__hip_bfloat16*)(ws + 4800000);
    float* hs = ws + 6400000;
    float* h1 = ws + 7400000;
    int* cnt    = (int*)(ws + 8400000);
    int* cursor = (int*)(ws + 8450000);
    int* off    = (int*)(ws + 8500000);
    float* cn   = ws + 8560000;
    int* flag   = (int*)(ws + 8560100);

    dim3 blk(256);
    hipMemsetAsync(cnt, 0, 2 * NN * sizeof(int), stream);  // cnt + cursor (adjacent)
    k_flag<<<1, 1, 0, stream>>>(flag, ei);
    k_cvt<<<(NE + 255) / 256, blk, 0, stream>>>(ei, flag, r32, c32, cnt);
    k_scan<<<1, 1024, 0, stream>>>(cnt, off);
    k_xw<<<(NN * 32 + 255) / 256, blk, 0, stream>>>(x, Wg, cnt, hs);
    k_fill<<<(NE + 255) / 256, blk, 0, stream>>>(r32, c32, off, cursor, re);
    k_gather<<<(NN * 32 + 255) / 256, blk, 0, stream>>>(off, re, cnt, hs, bg, h1);
    k_cn<<<1, 64, 0, stream>>>(h1, W1, b1, nid, cn);
    k_ab<<<(NN * 64 + 255) / 256, blk, 0, stream>>>(h1, W1, cn, A16, B16);
    k_edge<<<(NN * 16 + 255) / 256, blk, 0, stream>>>(off, re, A16, B16, W2, b2, eps, out);
}

// Round 4
// 520.554 us; speedup vs baseline: 1.1126x; 1.1126x over previous
//
#include <hip/hip_runtime.h>
#include <hip/hip_bf16.h>
#include <math.h>

#define NN 50000
#define NE 1600000
#define FIN 128
#define EH 20
#define DH 64

// ---------------- kernels ----------------

// zero cnt+cursor (adjacent, 2*NN ints) and detect edge_index width (int64 vs int32)
__global__ void k_init(int* cnt, int* flag, const void* ei) {
    int i = blockIdx.x * blockDim.x + threadIdx.x;
    if (i < 2 * NN) cnt[i] = 0;
    if (i == 0) {
        const int* w = (const int*)ei;
        int all0 = 1;
        for (int j = 1; j < 128; j += 2) all0 &= (w[j] == 0);
        *flag = all0;  // 1 => int64 layout (high words zero), 0 => int32
    }
}

// convert edge_index to int32 r/c arrays and count in-degree of col
__global__ void k_cvt(const void* ei, const int* flag, int* r32, int* c32, int* cnt) {
    int e = blockIdx.x * blockDim.x + threadIdx.x;
    if (e >= NE) return;
    int r, c;
    if (*flag) {
        const long long* p = (const long long*)ei;
        r = (int)p[e];
        c = (int)p[NE + e];
    } else {
        const int* p = (const int*)ei;
        r = p[e];
        c = p[NE + e];
    }
    r32[e] = r;
    c32[e] = c;
    atomicAdd(&cnt[c], 1);
}

// single-block exclusive scan of cnt[NN] -> off[NN+1]
__global__ void k_scan(const int* __restrict__ cnt, int* __restrict__ off) {
    __shared__ int part[1024];
    const int t = threadIdx.x;
    const int CH = (NN + 1023) / 1024;  // 49
    const int base = t * CH;
    int s = 0;
    for (int i = 0; i < CH; ++i) {
        int idx = base + i;
        if (idx < NN) s += cnt[idx];
    }
    part[t] = s;
    __syncthreads();
    for (int d = 1; d < 1024; d <<= 1) {
        int v = 0;
        if (t >= d) v = part[t - d];
        __syncthreads();
        if (t >= d) part[t] += v;
        __syncthreads();
    }
    int excl = (t == 0) ? 0 : part[t - 1];
    for (int i = 0; i < CH; ++i) {
        int idx = base + i;
        if (idx < NN) {
            off[idx] = excl;
            excl += cnt[idx];
        }
    }
    if (t == 1023) off[NN] = excl;  // == NE
}

// bucket-fill CSR: re[pos] = {r, e}, cpos[pos] = c
__global__ void k_fill(const int* __restrict__ r32, const int* __restrict__ c32,
                       const int* __restrict__ off, int* __restrict__ cursor,
                       int2* __restrict__ re, int* __restrict__ cpos) {
    int e = blockIdx.x * blockDim.x + threadIdx.x;
    if (e >= NE) return;
    int c = c32[e];
    int pos = off[c] + atomicAdd(&cursor[c], 1);
    re[pos] = make_int2(r32[e], e);
    cpos[pos] = c;
}

// hs[n*32+k] = dinv[n] * dot(x[n,:], W[:,k]) ; 20 lanes per node (padded 128B rows)
__global__ void k_xw(const float* __restrict__ x, const float* __restrict__ W,
                     const int* __restrict__ cnt, float* __restrict__ hs) {
    int t = blockIdx.x * blockDim.x + threadIdx.x;
    int n = t / EH;
    int k = t - n * EH;
    if (n >= NN) return;
    const float4* xr = (const float4*)(x + (size_t)n * FIN);
    float acc = 0.f;
#pragma unroll
    for (int j4 = 0; j4 < FIN / 4; ++j4) {
        float4 v = xr[j4];  // broadcast across the 20-lane group
        acc = fmaf(v.x, W[(4 * j4 + 0) * EH + k], acc);
        acc = fmaf(v.y, W[(4 * j4 + 1) * EH + k], acc);
        acc = fmaf(v.z, W[(4 * j4 + 2) * EH + k], acc);
        acc = fmaf(v.w, W[(4 * j4 + 3) * EH + k], acc);
    }
    float dinv = rsqrtf(1.0f + (float)cnt[n]);
    hs[n * 32 + k] = dinv * acc;
}

// per-node gather + bias + relu; 20 lanes per node
__global__ void k_gather(const int* __restrict__ off, const int2* __restrict__ re,
                         const int* __restrict__ cnt, const float* __restrict__ hs,
                         const float* __restrict__ bg, float* __restrict__ h1) {
    int t = blockIdx.x * blockDim.x + threadIdx.x;
    int n = t / EH;
    int k = t - n * EH;
    if (n >= NN) return;
    float acc = hs[n * 32 + k];  // self-loop term (already carries dinv[n])
    int e0 = off[n], e1 = off[n + 1];
    for (int e = e0; e < e1; ++e) {
        int r = re[e].x;               // broadcast across group
        acc += hs[r * 32 + k];         // one aligned 128B row per edge
    }
    float dinv = rsqrtf(1.0f + (float)cnt[n]);
    h1[n * EH + k] = fmaxf(fmaf(dinv, acc, bg[k]), 0.f);
}

// cn[j] = h1[node_id,:] @ W1[40:60, j] + b1[j]
__global__ void k_cn(const float* __restrict__ h1, const float* __restrict__ W1,
                     const float* __restrict__ b1, const void* nid_p,
                     float* __restrict__ cn) {
    int j = threadIdx.x;  // 64 threads
    int nid = *(const int*)nid_p;  // low 32 bits valid for int32 or int64 LE
    const float* hr = h1 + (size_t)nid * EH;
    float acc = b1[j];
#pragma unroll
    for (int k = 0; k < EH; ++k) acc = fmaf(hr[k], W1[(2 * EH + k) * DH + j], acc);
    cn[j] = acc;
}

// A16[n,j] = bf16(h1[n,:] @ W1[0:20, j]);  Bf[n,j] = cn[j] + h1[n,:] @ W1[20:40, j]
__global__ void k_ab(const float* __restrict__ h1, const float* __restrict__ W1,
                     const float* __restrict__ cn,
                     __hip_bfloat16* __restrict__ A16, float* __restrict__ Bf) {
    int t = blockIdx.x * blockDim.x + threadIdx.x;
    int n = t >> 6;
    int j = t & 63;
    if (n >= NN) return;
    const float* hr = h1 + (size_t)n * EH;
    float a = 0.f, b = cn[j];
#pragma unroll
    for (int k = 0; k < EH; ++k) {
        float hv = hr[k];
        a = fmaf(hv, W1[k * DH + j], a);
        b = fmaf(hv, W1[(EH + k) * DH + j], b);
    }
    A16[(size_t)n * DH + j] = __float2bfloat16(a);
    Bf[(size_t)n * DH + j] = b;
}

// per-CSR-position edge decoder: 1 thread per edge, full 64-dot in-thread.
__global__ void k_edge(const int2* __restrict__ re, const int* __restrict__ cpos,
                       const __hip_bfloat16* __restrict__ A16,
                       const float* __restrict__ Bf,
                       const float* __restrict__ W2, const float* __restrict__ b2,
                       const float* __restrict__ eps, float* __restrict__ out) {
    int p = blockIdx.x * blockDim.x + threadIdx.x;
    if (p >= NE) return;
    int2 pe = re[p];
    int c = cpos[p];
    const uint4* arow = (const uint4*)(A16 + (size_t)pe.x * DH);
    const float4* brow = (const float4*)(Bf + (size_t)c * DH);
    float acc = 0.f;
#pragma unroll
    for (int j = 0; j < 8; ++j) {
        uint4 av = arow[j];
        float4 b0 = brow[2 * j];
        float4 b1 = brow[2 * j + 1];
        float a0 = __uint_as_float(av.x << 16);
        float a1 = __uint_as_float(av.x & 0xffff0000u);
        float a2 = __uint_as_float(av.y << 16);
        float a3 = __uint_as_float(av.y & 0xffff0000u);
        float a4 = __uint_as_float(av.z << 16);
        float a5 = __uint_as_float(av.z & 0xffff0000u);
        float a6 = __uint_as_float(av.w << 16);
        float a7 = __uint_as_float(av.w & 0xffff0000u);
        acc = fmaf(fmaxf(a0 + b0.x, 0.f), W2[8 * j + 0], acc);
        acc = fmaf(fmaxf(a1 + b0.y, 0.f), W2[8 * j + 1], acc);
        acc = fmaf(fmaxf(a2 + b0.z, 0.f), W2[8 * j + 2], acc);
        acc = fmaf(fmaxf(a3 + b0.w, 0.f), W2[8 * j + 3], acc);
        acc = fmaf(fmaxf(a4 + b1.x, 0.f), W2[8 * j + 4], acc);
        acc = fmaf(fmaxf(a5 + b1.y, 0.f), W2[8 * j + 5], acc);
        acc = fmaf(fmaxf(a6 + b1.z, 0.f), W2[8 * j + 6], acc);
        acc = fmaf(fmaxf(a7 + b1.w, 0.f), W2[8 * j + 7], acc);
    }
    float ep = eps[pe.y];
    // e = (bias-(1-bias))*eps + (1-bias), bias=1e-4
    float ee = fmaf(-0.9998f, ep, 0.9999f);
    float gate = logf(ee) - log1pf(-ee) + acc + b2[0];
    out[pe.y] = 1.0f / (1.0f + expf(-gate));
}

// ---------------- launch ----------------

extern "C" void kernel_launch(void* const* d_in, const int* in_sizes, int n_in,
                              void* d_out, int out_size, void* d_ws, size_t ws_size,
                              hipStream_t stream) {
    const float* x   = (const float*)d_in[0];
    const void*  ei  = d_in[1];
    const void*  nid = d_in[2];
    const float* eps = (const float*)d_in[3];
    const float* Wg  = (const float*)d_in[4];
    const float* bg  = (const float*)d_in[5];
    const float* W1  = (const float*)d_in[6];
    const float* b1  = (const float*)d_in[7];
    const float* W2  = (const float*)d_in[8];
    const float* b2  = (const float*)d_in[9];
    float* out = (float*)d_out;

    float* ws = (float*)d_ws;
    // Timeline-aliased layout (floats):
    //   [0,3.2M)    re      (fill -> edge)
    //   [3.2,4.8M)  cpos    (fill -> edge)
    //   [4.8,6.4M)  r32 (cvt->fill) then hs (xw->gather) then A16 (ab->edge)
    //   [6.4,8.0M)  c32 (cvt->fill) then h1 (gather->ab)
    //   [8.0,11.2M) Bf      (ab -> edge)
    //   [11.2M+)    cnt, cursor, off, cn, flag
    int2* re   = (int2*)(ws + 0);
    int*  cpos = (int*)(ws + 3200000);
    int*  r32  = (int*)(ws + 4800000);
    float* hs  = ws + 4800000;          // NN*32 = 1.6M
    __hip_bfloat16* A16 = (__hip_bfloat16*)(ws + 4800000);  // NN*64 bf16 = 1.6M floats
    int*  c32  = (int*)(ws + 6400000);
    float* h1  = ws + 6400000;          // NN*20 = 1.0M
    float* Bf  = ws + 8000000;          // NN*64 = 3.2M
    int* cnt    = (int*)(ws + 11200000);
    int* cursor = (int*)(ws + 11250000);
    int* off    = (int*)(ws + 11300000);
    float* cn   = ws + 11360000;
    int* flag   = (int*)(ws + 11360100);

    dim3 blk(256);
    k_init<<<(2 * NN + 255) / 256, blk, 0, stream>>>(cnt, flag, ei);
    k_cvt<<<(NE + 255) / 256, blk, 0, stream>>>(ei, flag, r32, c32, cnt);
    k_scan<<<1, 1024, 0, stream>>>(cnt, off);
    k_fill<<<(NE + 255) / 256, blk, 0, stream>>>(r32, c32, off, cursor, re, cpos);
    k_xw<<<(NN * EH + 255) / 256, blk, 0, stream>>>(x, Wg, cnt, hs);
    k_gather<<<(NN * EH + 255) / 256, blk, 0, stream>>>(off, re, cnt, hs, bg, h1);
    k_cn<<<1, 64, 0, stream>>>(h1, W1, b1, nid, cn);
    k_ab<<<(NN * 64 + 255) / 256, blk, 0, stream>>>(h1, W1, cn, A16, Bf);
    k_edge<<<(NE + 255) / 256, blk, 0, stream>>>(re, cpos, A16, Bf, W2, b2, eps, out);
}

// Round 5
// 460.444 us; speedup vs baseline: 1.2578x; 1.1305x over previous
//
#include <hip/hip_runtime.h>
#include <hip/hip_bf16.h>
#include <math.h>

#define NN 50000
#define NE 1600000
#define FIN 128
#define EH 20
#define DH 64

// ---------------- kernels ----------------

// zero cnt+cursor (adjacent, 2*NN ints) and detect edge_index width (int64 vs int32)
__global__ void k_init(int* cnt, int* flag, const void* ei) {
    int i = blockIdx.x * blockDim.x + threadIdx.x;
    if (i < 2 * NN) cnt[i] = 0;
    if (i == 0) {
        const int* w = (const int*)ei;
        int all0 = 1;
        for (int j = 1; j < 128; j += 2) all0 &= (w[j] == 0);
        *flag = all0;  // 1 => int64 layout (high words zero), 0 => int32
    }
}

// convert edge_index to int32 r/c arrays and count in-degree of col
__global__ void k_cvt(const void* ei, const int* flag, int* r32, int* c32, int* cnt) {
    int e = blockIdx.x * blockDim.x + threadIdx.x;
    if (e >= NE) return;
    int r, c;
    if (*flag) {
        const long long* p = (const long long*)ei;
        r = (int)p[e];
        c = (int)p[NE + e];
    } else {
        const int* p = (const int*)ei;
        r = p[e];
        c = p[NE + e];
    }
    r32[e] = r;
    c32[e] = c;
    atomicAdd(&cnt[c], 1);
}

// single-block exclusive scan of cnt[NN] -> off[NN+1]
__global__ void k_scan(const int* __restrict__ cnt, int* __restrict__ off) {
    __shared__ int part[1024];
    const int t = threadIdx.x;
    const int CH = (NN + 1023) / 1024;  // 49
    const int base = t * CH;
    int s = 0;
    for (int i = 0; i < CH; ++i) {
        int idx = base + i;
        if (idx < NN) s += cnt[idx];
    }
    part[t] = s;
    __syncthreads();
    for (int d = 1; d < 1024; d <<= 1) {
        int v = 0;
        if (t >= d) v = part[t - d];
        __syncthreads();
        if (t >= d) part[t] += v;
        __syncthreads();
    }
    int excl = (t == 0) ? 0 : part[t - 1];
    for (int i = 0; i < CH; ++i) {
        int idx = base + i;
        if (idx < NN) {
            off[idx] = excl;
            excl += cnt[idx];
        }
    }
    if (t == 1023) off[NN] = excl;  // == NE
}

// bucket-fill CSR: src[off[c] + cursor[c]++] = r   (4B/edge scatter)
__global__ void k_fill(const int* __restrict__ r32, const int* __restrict__ c32,
                       const int* __restrict__ off, int* __restrict__ cursor,
                       int* __restrict__ src) {
    int e = blockIdx.x * blockDim.x + threadIdx.x;
    if (e >= NE) return;
    int c = c32[e];
    int pos = off[c] + atomicAdd(&cursor[c], 1);
    src[pos] = r32[e];
}

// hs16[n*32+k] = bf16(dinv[n] * dot(x[n,:], W[:,k])) ; 20 lanes per node (64B rows)
__global__ void k_xw(const float* __restrict__ x, const float* __restrict__ W,
                     const int* __restrict__ cnt, __hip_bfloat16* __restrict__ hs16) {
    int t = blockIdx.x * blockDim.x + threadIdx.x;
    int n = t / EH;
    int k = t - n * EH;
    if (n >= NN) return;
    const float4* xr = (const float4*)(x + (size_t)n * FIN);
    float acc = 0.f;
#pragma unroll
    for (int j4 = 0; j4 < FIN / 4; ++j4) {
        float4 v = xr[j4];  // broadcast across the 20-lane group
        acc = fmaf(v.x, W[(4 * j4 + 0) * EH + k], acc);
        acc = fmaf(v.y, W[(4 * j4 + 1) * EH + k], acc);
        acc = fmaf(v.z, W[(4 * j4 + 2) * EH + k], acc);
        acc = fmaf(v.w, W[(4 * j4 + 3) * EH + k], acc);
    }
    float dinv = rsqrtf(1.0f + (float)cnt[n]);
    hs16[n * 32 + k] = __float2bfloat16(dinv * acc);
}

// per-node gather + bias + relu; 20 lanes per node
__global__ void k_gather(const int* __restrict__ off, const int* __restrict__ src,
                         const int* __restrict__ cnt,
                         const __hip_bfloat16* __restrict__ hs16,
                         const float* __restrict__ bg, float* __restrict__ h1) {
    int t = blockIdx.x * blockDim.x + threadIdx.x;
    int n = t / EH;
    int k = t - n * EH;
    if (n >= NN) return;
    const unsigned short* hu = (const unsigned short*)hs16;
    float acc = __uint_as_float((unsigned)hu[n * 32 + k] << 16);  // self-loop term
    int e0 = off[n], e1 = off[n + 1];
    for (int e = e0; e < e1; ++e) {
        int r = src[e];                // broadcast across group
        acc += __uint_as_float((unsigned)hu[r * 32 + k] << 16);
    }
    float dinv = rsqrtf(1.0f + (float)cnt[n]);
    h1[n * EH + k] = fmaxf(fmaf(dinv, acc, bg[k]), 0.f);
}

// A16[n,j] = bf16(h1[n,:] @ W1[0:20, j]);
// B16[n,j] = bf16(b1[j] + h1[nid,:] @ W1[40:60, j] + h1[n,:] @ W1[20:40, j])
__global__ void k_ab(const float* __restrict__ h1, const float* __restrict__ W1,
                     const float* __restrict__ b1, const void* nid_p,
                     __hip_bfloat16* __restrict__ A16, __hip_bfloat16* __restrict__ B16) {
    int t = blockIdx.x * blockDim.x + threadIdx.x;
    int n = t >> 6;
    int j = t & 63;
    if (n >= NN) return;
    int nid = *(const int*)nid_p;  // low 32 bits valid for int32 or int64 LE
    const float* hr = h1 + (size_t)n * EH;
    const float* hn = h1 + (size_t)nid * EH;  // broadcast
    float a = 0.f, b = b1[j];
#pragma unroll
    for (int k = 0; k < EH; ++k) {
        float hv = hr[k];
        a = fmaf(hv, W1[k * DH + j], a);
        b = fmaf(hv, W1[(EH + k) * DH + j], b);
        b = fmaf(hn[k], W1[(2 * EH + k) * DH + j], b);
    }
    A16[(size_t)n * DH + j] = __float2bfloat16(a);
    B16[(size_t)n * DH + j] = __float2bfloat16(b);
}

// per-edge decoder: 1 thread per edge, edge order (sequential eps/out).
__global__ void k_edge(const int* __restrict__ r32, const int* __restrict__ c32,
                       const __hip_bfloat16* __restrict__ A16,
                       const __hip_bfloat16* __restrict__ B16,
                       const float* __restrict__ W2, const float* __restrict__ b2,
                       const float* __restrict__ eps, float* __restrict__ out) {
    int e = blockIdx.x * blockDim.x + threadIdx.x;
    if (e >= NE) return;
    int r = r32[e], c = c32[e];
    const uint4* arow = (const uint4*)(A16 + (size_t)r * DH);
    const uint4* brow = (const uint4*)(B16 + (size_t)c * DH);
    float acc = 0.f;
#pragma unroll
    for (int j = 0; j < 8; ++j) {
        uint4 av = arow[j];
        uint4 bv = brow[j];
        float a0 = __uint_as_float(av.x << 16);
        float a1 = __uint_as_float(av.x & 0xffff0000u);
        float a2 = __uint_as_float(av.y << 16);
        float a3 = __uint_as_float(av.y & 0xffff0000u);
        float a4 = __uint_as_float(av.z << 16);
        float a5 = __uint_as_float(av.z & 0xffff0000u);
        float a6 = __uint_as_float(av.w << 16);
        float a7 = __uint_as_float(av.w & 0xffff0000u);
        float b0 = __uint_as_float(bv.x << 16);
        float b1v = __uint_as_float(bv.x & 0xffff0000u);
        float b2v = __uint_as_float(bv.y << 16);
        float b3 = __uint_as_float(bv.y & 0xffff0000u);
        float b4 = __uint_as_float(bv.z << 16);
        float b5 = __uint_as_float(bv.z & 0xffff0000u);
        float b6 = __uint_as_float(bv.w << 16);
        float b7 = __uint_as_float(bv.w & 0xffff0000u);
        acc = fmaf(fmaxf(a0 + b0,  0.f), W2[8 * j + 0], acc);
        acc = fmaf(fmaxf(a1 + b1v, 0.f), W2[8 * j + 1], acc);
        acc = fmaf(fmaxf(a2 + b2v, 0.f), W2[8 * j + 2], acc);
        acc = fmaf(fmaxf(a3 + b3,  0.f), W2[8 * j + 3], acc);
        acc = fmaf(fmaxf(a4 + b4,  0.f), W2[8 * j + 4], acc);
        acc = fmaf(fmaxf(a5 + b5,  0.f), W2[8 * j + 5], acc);
        acc = fmaf(fmaxf(a6 + b6,  0.f), W2[8 * j + 6], acc);
        acc = fmaf(fmaxf(a7 + b7,  0.f), W2[8 * j + 7], acc);
    }
    float ep = eps[e];
    // e = (bias-(1-bias))*eps + (1-bias), bias=1e-4
    float ee = fmaf(-0.9998f, ep, 0.9999f);
    float gate = logf(ee) - log1pf(-ee) + acc + b2[0];
    out[e] = 1.0f / (1.0f + expf(-gate));
}

// ---------------- launch ----------------

extern "C" void kernel_launch(void* const* d_in, const int* in_sizes, int n_in,
                              void* d_out, int out_size, void* d_ws, size_t ws_size,
                              hipStream_t stream) {
    const float* x   = (const float*)d_in[0];
    const void*  ei  = d_in[1];
    const void*  nid = d_in[2];
    const float* eps = (const float*)d_in[3];
    const float* Wg  = (const float*)d_in[4];
    const float* bg  = (const float*)d_in[5];
    const float* W1  = (const float*)d_in[6];
    const float* b1  = (const float*)d_in[7];
    const float* W2  = (const float*)d_in[8];
    const float* b2  = (const float*)d_in[9];
    float* out = (float*)d_out;

    float* ws = (float*)d_ws;
    // No aliasing needed: total ~9.9M floats ≈ 40 MB.
    int*  src  = (int*)(ws + 0);                           // 1.6M
    int*  r32  = (int*)(ws + 1600000);                     // 1.6M
    int*  c32  = (int*)(ws + 3200000);                     // 1.6M
    __hip_bfloat16* hs16 = (__hip_bfloat16*)(ws + 4800000); // NN*32 bf16 = 0.8M floats
    float* h1  = ws + 5600000;                             // NN*20 = 1.0M
    __hip_bfloat16* A16 = (__hip_bfloat16*)(ws + 6600000); // NN*64 bf16 = 1.6M floats
    __hip_bfloat16* B16 = (__hip_bfloat16*)(ws + 8200000); // 1.6M floats
    int* cnt    = (int*)(ws + 9800000);
    int* cursor = (int*)(ws + 9850000);
    int* off    = (int*)(ws + 9900000);
    int* flag   = (int*)(ws + 9960000);

    dim3 blk(256);
    k_init<<<(2 * NN + 255) / 256, blk, 0, stream>>>(cnt, flag, ei);
    k_cvt<<<(NE + 255) / 256, blk, 0, stream>>>(ei, flag, r32, c32, cnt);
    k_scan<<<1, 1024, 0, stream>>>(cnt, off);
    k_fill<<<(NE + 255) / 256, blk, 0, stream>>>(r32, c32, off, cursor, src);
    k_xw<<<(NN * EH + 255) / 256, blk, 0, stream>>>(x, Wg, cnt, hs16);
    k_gather<<<(NN * EH + 255) / 256, blk, 0, stream>>>(off, src, cnt, hs16, bg, h1);
    k_ab<<<(NN * 64 + 255) / 256, blk, 0, stream>>>(h1, W1, b1, nid, A16, B16);
    k_edge<<<(NE + 255) / 256, blk, 0, stream>>>(r32, c32, A16, B16, W2, b2, eps, out);
}